// Round 1
// baseline (577.317 us; speedup 1.0000x reference)
//
#include <hip/hip_runtime.h>
#include <hip/hip_bf16.h>

#define NB 8
#define C 256
#define LL 6400
#define HEADS 8
#define HC 32
#define NH 64      // NB*HEADS
#define CH 40      // l-chunks for context partials
#define CHUNK 160  // LL / CH

typedef unsigned short u16;
typedef unsigned int u32;

__device__ __forceinline__ float bf2f(u32 u) { return __uint_as_float(u << 16); }
__device__ __forceinline__ u16 f2bf(float f) {
  __hip_bfloat16 h = __float2bfloat16(f);
  return *(u16*)&h;
}
__device__ __forceinline__ void unpack8(uint4 u, float* f) {
  f[0] = bf2f(u.x & 0xffffu); f[1] = bf2f(u.x >> 16);
  f[2] = bf2f(u.y & 0xffffu); f[3] = bf2f(u.y >> 16);
  f[4] = bf2f(u.z & 0xffffu); f[5] = bf2f(u.z >> 16);
  f[6] = bf2f(u.w & 0xffffu); f[7] = bf2f(u.w >> 16);
}

// ---------------- projection GEMM: P[n] = W @ X[n] + b, bf16 out ----------------
// 128x128 tile, BK=8, 256 threads, 8x8 per thread.
__global__ __launch_bounds__(256) void proj_kernel(const float* __restrict__ X,
    const float* __restrict__ W, const float* __restrict__ bias,
    u16* __restrict__ P)
{
  __shared__ float As[8][132];  // [k][co], pad to 132 for bank spread
  __shared__ float Bs[8][128];  // [k][l]
  const int n = blockIdx.z;
  const int co0 = blockIdx.y * 128;
  const int l0 = blockIdx.x * 128;
  const int t = threadIdx.x;
  const int tx = t & 15, ty = t >> 4;
  const float* Xn = X + (size_t)n * C * LL;
  float acc[8][8];
#pragma unroll
  for (int i = 0; i < 8; ++i)
#pragma unroll
    for (int j = 0; j < 8; ++j) acc[i][j] = 0.f;
  const int a_co = t >> 1;        // 0..127
  const int a_k = (t & 1) * 4;    // 0 or 4
  const int b_k = t >> 5;         // 0..7
  const int b_l = (t & 31) * 4;   // 0..124
  for (int k0 = 0; k0 < C; k0 += 8) {
    float4 av = *(const float4*)&W[(size_t)(co0 + a_co) * C + k0 + a_k];
    float4 bv = *(const float4*)&Xn[(size_t)(k0 + b_k) * LL + l0 + b_l];
    __syncthreads();
    As[a_k + 0][a_co] = av.x; As[a_k + 1][a_co] = av.y;
    As[a_k + 2][a_co] = av.z; As[a_k + 3][a_co] = av.w;
    *(float4*)&Bs[b_k][b_l] = bv;
    __syncthreads();
#pragma unroll
    for (int kk = 0; kk < 8; ++kk) {
      float a[8], b[8];
      *(float4*)&a[0] = *(const float4*)&As[kk][ty * 8];
      *(float4*)&a[4] = *(const float4*)&As[kk][ty * 8 + 4];
      *(float4*)&b[0] = *(const float4*)&Bs[kk][tx * 8];
      *(float4*)&b[4] = *(const float4*)&Bs[kk][tx * 8 + 4];
#pragma unroll
      for (int i = 0; i < 8; ++i)
#pragma unroll
        for (int j = 0; j < 8; ++j) acc[i][j] = fmaf(a[i], b[j], acc[i][j]);
    }
  }
  u16* Pn = P + (size_t)n * C * LL;
#pragma unroll
  for (int i = 0; i < 8; ++i) {
    const int co = co0 + ty * 8 + i;
    const float bi = bias[co];
    union { uint4 u; u16 h[8]; } pk;
#pragma unroll
    for (int j = 0; j < 8; ++j) pk.h[j] = f2bf(acc[i][j] + bi);
    *(uint4*)&Pn[(size_t)co * LL + l0 + tx * 8] = pk.u;
  }
}

// ---------------- k row stats: max + 1/sum(exp) over L per (n,channel) ----------------
__global__ __launch_bounds__(256) void kstats_kernel(const u16* __restrict__ Kb,
    float* __restrict__ kmax, float* __restrict__ krs)
{
  const int row = blockIdx.x;  // 0..NB*C-1
  const u16* kr = Kb + (size_t)row * LL;
  const int t = threadIdx.x;
  float v[25];
  float mx = -1e30f;
#pragma unroll
  for (int i = 0; i < 25; ++i) { v[i] = bf2f(kr[t + i * 256]); mx = fmaxf(mx, v[i]); }
#pragma unroll
  for (int o = 32; o > 0; o >>= 1) mx = fmaxf(mx, __shfl_down(mx, o));
  __shared__ float red[8];
  if ((t & 63) == 0) red[t >> 6] = mx;
  __syncthreads();
  mx = fmaxf(fmaxf(red[0], red[1]), fmaxf(red[2], red[3]));
  float s = 0.f;
#pragma unroll
  for (int i = 0; i < 25; ++i) s += expf(v[i] - mx);
#pragma unroll
  for (int o = 32; o > 0; o >>= 1) s += __shfl_down(s, o);
  if ((t & 63) == 0) red[4 + (t >> 6)] = s;
  __syncthreads();
  if (t == 0) { kmax[row] = mx; krs[row] = 1.f / (red[4] + red[5] + red[6] + red[7]); }
}

// ---------------- q softmax over 32 head-channels, in place ----------------
__global__ __launch_bounds__(256) void qsoftmax_kernel(u16* __restrict__ Q)
{
  const int idx = blockIdx.x * 256 + threadIdx.x;  // < NH*LL
  const int l = idx % LL;
  const int nh = idx / LL;
  u16* base = Q + (size_t)nh * HC * LL + l;
  float v[HC];
  float mx = -1e30f;
#pragma unroll
  for (int c = 0; c < HC; ++c) { v[c] = bf2f(base[(size_t)c * LL]); mx = fmaxf(mx, v[c]); }
  float s = 0.f;
#pragma unroll
  for (int c = 0; c < HC; ++c) { v[c] = expf(v[c] - mx); s += v[c]; }
  const float r = 1.f / s;
#pragma unroll
  for (int c = 0; c < HC; ++c) base[(size_t)c * LL] = f2bf(v[c] * r);
}

// ---------------- context partials: ctx[k,v] += softmax(K)[k,l] * V[v,l] ----------------
// grid (CH, NH), 1 wave per block; lane computes 4x4 of the 32x32 tile.
__global__ __launch_bounds__(64) void ctx_partial_kernel(const u16* __restrict__ Kb,
    const u16* __restrict__ Vb, const float* __restrict__ kmax,
    const float* __restrict__ krs, float* __restrict__ part)
{
  __shared__ float Ks[32][36];  // [l][k]
  __shared__ float Vs[32][36];  // [l][v]
  const int nh = blockIdx.y;
  const int chk = blockIdx.x;
  const int lane = threadIdx.x;
  const size_t base = (size_t)nh * HC * LL;
  const int c = lane >> 1;          // channel 0..31
  const int lh = (lane & 1) * 16;   // l-half
  const float km = kmax[nh * HC + c];
  const int k4 = (lane & 7) * 4;
  const int v4 = (lane >> 3) * 4;
  float acc[4][4];
#pragma unroll
  for (int i = 0; i < 4; ++i)
#pragma unroll
    for (int j = 0; j < 4; ++j) acc[i][j] = 0.f;
  for (int ls = 0; ls < CHUNK; ls += 32) {
    const size_t off = base + (size_t)c * LL + chk * CHUNK + ls + lh;
    uint4 ka = *(const uint4*)&Kb[off];
    uint4 kb = *(const uint4*)&Kb[off + 8];
    uint4 va = *(const uint4*)&Vb[off];
    uint4 vb = *(const uint4*)&Vb[off + 8];
    float kf[16], vf[16];
    unpack8(ka, kf); unpack8(kb, kf + 8);
    unpack8(va, vf); unpack8(vb, vf + 8);
    __syncthreads();
#pragma unroll
    for (int j = 0; j < 16; ++j) {
      Ks[lh + j][c] = expf(kf[j] - km);
      Vs[lh + j][c] = vf[j];
    }
    __syncthreads();
#pragma unroll
    for (int l = 0; l < 32; ++l) {
      float a[4], b[4];
      *(float4*)a = *(const float4*)&Ks[l][k4];
      *(float4*)b = *(const float4*)&Vs[l][v4];
#pragma unroll
      for (int i = 0; i < 4; ++i)
#pragma unroll
        for (int j = 0; j < 4; ++j) acc[i][j] = fmaf(a[i], b[j], acc[i][j]);
    }
  }
#pragma unroll
  for (int i = 0; i < 4; ++i) {
    const float rs = krs[nh * HC + k4 + i];
#pragma unroll
    for (int j = 0; j < 4; ++j)
      part[(((size_t)chk * NH + nh) * HC + k4 + i) * HC + v4 + j] = acc[i][j] * rs;
  }
}

__global__ __launch_bounds__(256) void ctx_reduce_kernel(const float* __restrict__ part,
                                                         float* __restrict__ ctx)
{
  const int idx = blockIdx.x * 256 + threadIdx.x;  // < NH*HC*HC
  float s = 0.f;
  for (int c = 0; c < CH; ++c) s += part[(size_t)c * (NH * HC * HC) + idx];
  ctx[idx] = s;
}

// ---------------- fuse: M_n[o, h*32+k] = sum_v Wr[o, h*32+v] * ctx[n,h,k,v] ----------------
__global__ __launch_bounds__(256) void mfuse_kernel(const float* __restrict__ Wr,
    const float* __restrict__ ctx, float* __restrict__ M)
{
  const int idx = blockIdx.x * 256 + threadIdx.x;  // < NB*C*C
  const int hk = idx & 255;
  const int o = (idx >> 8) & 255;
  const int n = idx >> 16;
  const int h = hk >> 5, k = hk & 31;
  const float* wr = Wr + (size_t)o * C + h * HC;
  const float* cx = ctx + ((size_t)(n * HEADS + h) * HC + k) * HC;
  float s = 0.f;
#pragma unroll
  for (int v = 0; v < HC; ++v) s = fmaf(wr[v], cx[v], s);
  M[idx] = s;
}

// ---------------- out[n] = M_n @ Qsm[n] + br + Xq[n], fp32 out ----------------
__global__ __launch_bounds__(256) void out_kernel(const u16* __restrict__ Q,
    const float* __restrict__ M, const float* __restrict__ br,
    const float* __restrict__ Xq, float* __restrict__ out)
{
  __shared__ float As[8][132];
  __shared__ float Bs[8][128];
  const int n = blockIdx.z;
  const int co0 = blockIdx.y * 128;
  const int l0 = blockIdx.x * 128;
  const int t = threadIdx.x;
  const int tx = t & 15, ty = t >> 4;
  const float* Mn = M + (size_t)n * C * C;
  const u16* Qn = Q + (size_t)n * C * LL;
  float acc[8][8];
#pragma unroll
  for (int i = 0; i < 8; ++i)
#pragma unroll
    for (int j = 0; j < 8; ++j) acc[i][j] = 0.f;
  const int a_co = t >> 1;
  const int a_k = (t & 1) * 4;
  const int b_k = t >> 5;
  const int b_l = (t & 31) * 4;
  for (int k0 = 0; k0 < C; k0 += 8) {
    float4 av = *(const float4*)&Mn[(size_t)(co0 + a_co) * C + k0 + a_k];
    ushort4 qv = *(const ushort4*)&Qn[(size_t)(k0 + b_k) * LL + l0 + b_l];
    __syncthreads();
    As[a_k + 0][a_co] = av.x; As[a_k + 1][a_co] = av.y;
    As[a_k + 2][a_co] = av.z; As[a_k + 3][a_co] = av.w;
    float4 bv = make_float4(bf2f(qv.x), bf2f(qv.y), bf2f(qv.z), bf2f(qv.w));
    *(float4*)&Bs[b_k][b_l] = bv;
    __syncthreads();
#pragma unroll
    for (int kk = 0; kk < 8; ++kk) {
      float a[8], b[8];
      *(float4*)&a[0] = *(const float4*)&As[kk][ty * 8];
      *(float4*)&a[4] = *(const float4*)&As[kk][ty * 8 + 4];
      *(float4*)&b[0] = *(const float4*)&Bs[kk][tx * 8];
      *(float4*)&b[4] = *(const float4*)&Bs[kk][tx * 8 + 4];
#pragma unroll
      for (int i = 0; i < 8; ++i)
#pragma unroll
        for (int j = 0; j < 8; ++j) acc[i][j] = fmaf(a[i], b[j], acc[i][j]);
    }
  }
  const float* Xn = Xq + (size_t)n * C * LL;
  float* On = out + (size_t)n * C * LL;
#pragma unroll
  for (int i = 0; i < 8; ++i) {
    const int co = co0 + ty * 8 + i;
    const float bi = br[co];
    const size_t off = (size_t)co * LL + l0 + tx * 8;
    float4 x0 = *(const float4*)&Xn[off];
    float4 x1 = *(const float4*)&Xn[off + 4];
    float4 r0 = make_float4(acc[i][0] + bi + x0.x, acc[i][1] + bi + x0.y,
                            acc[i][2] + bi + x0.z, acc[i][3] + bi + x0.w);
    float4 r1 = make_float4(acc[i][4] + bi + x1.x, acc[i][5] + bi + x1.y,
                            acc[i][6] + bi + x1.z, acc[i][7] + bi + x1.w);
    *(float4*)&On[off] = r0;
    *(float4*)&On[off + 4] = r1;
  }
}

extern "C" void kernel_launch(void* const* d_in, const int* in_sizes, int n_in,
                              void* d_out, int out_size, void* d_ws, size_t ws_size,
                              hipStream_t stream) {
  const float* Xq = (const float*)d_in[0];
  const float* Xk = (const float*)d_in[1];
  const float* Xv = (const float*)d_in[2];
  const float* Wq = (const float*)d_in[3];
  const float* bq = (const float*)d_in[4];
  const float* Wk = (const float*)d_in[5];
  const float* bk = (const float*)d_in[6];
  const float* Wv = (const float*)d_in[7];
  const float* bv = (const float*)d_in[8];
  const float* Wr = (const float*)d_in[9];
  const float* br = (const float*)d_in[10];
  float* out = (float*)d_out;

  char* ws = (char*)d_ws;
  const size_t qkv = (size_t)NB * C * LL;  // elements per projection buffer
  u16* Qb = (u16*)ws;
  u16* Kb = (u16*)(ws + qkv * 2);
  u16* Vb = (u16*)(ws + qkv * 4);
  float* kmax = (float*)(ws + qkv * 6);
  float* krs = kmax + NB * C;
  float* ctx = krs + NB * C;                       // 65536 floats
  float* part = ctx + NB * HEADS * HC * HC;        // CH*NH*1024 floats
  float* Mfused = part + (size_t)CH * NH * HC * HC;  // NB*C*C floats

  dim3 g(50, 2, NB);
  proj_kernel<<<g, 256, 0, stream>>>(Xq, Wq, bq, Qb);
  proj_kernel<<<g, 256, 0, stream>>>(Xk, Wk, bk, Kb);
  proj_kernel<<<g, 256, 0, stream>>>(Xv, Wv, bv, Vb);
  kstats_kernel<<<NB * C, 256, 0, stream>>>(Kb, kmax, krs);
  qsoftmax_kernel<<<NH * LL / 256, 256, 0, stream>>>(Qb);
  ctx_partial_kernel<<<dim3(CH, NH), 64, 0, stream>>>(Kb, Vb, kmax, krs, part);
  ctx_reduce_kernel<<<NH * HC * HC / 256, 256, 0, stream>>>(part, ctx);
  mfuse_kernel<<<NB * C * C / 256, 256, 0, stream>>>(Wr, ctx, Mfused);
  out_kernel<<<g, 256, 0, stream>>>(Qb, Mfused, br, Xq, out);
}

// Round 2
// 359.131 us; speedup vs baseline: 1.6075x; 1.6075x over previous
//
#include <hip/hip_runtime.h>
#include <hip/hip_bf16.h>

#define NB 8
#define C 256
#define LL 6400
#define HEADS 8
#define HC 32
#define NH 64      // NB*HEADS
#define CH 40      // l-chunks for context partials
#define CHUNK 160  // LL / CH
#define KCHUNKS 25 // kstats l-chunks of 256

typedef unsigned short u16;
typedef unsigned int u32;
typedef __attribute__((ext_vector_type(8))) short bf16x8;
typedef __attribute__((ext_vector_type(4))) float f32x4;

typedef __attribute__((address_space(1))) const u32 ga_u32;
typedef __attribute__((address_space(3))) u32 ls_u32;

__device__ __forceinline__ void gload_lds16(const u16* g, u16* l) {
  __builtin_amdgcn_global_load_lds((ga_u32*)g, (ls_u32*)l, 16, 0, 0);
}

__device__ __forceinline__ float bf2f(u32 u) { return __uint_as_float(u << 16); }
__device__ __forceinline__ u16 f2bf(float f) {
  __hip_bfloat16 h = __float2bfloat16(f);
  return *(u16*)&h;
}
__device__ __forceinline__ void unpack8(uint4 u, float* f) {
  f[0] = bf2f(u.x & 0xffffu); f[1] = bf2f(u.x >> 16);
  f[2] = bf2f(u.y & 0xffffu); f[3] = bf2f(u.y >> 16);
  f[4] = bf2f(u.z & 0xffffu); f[5] = bf2f(u.z >> 16);
  f[6] = bf2f(u.w & 0xffffu); f[7] = bf2f(u.w >> 16);
}

// ---------------- fp32 [C][L] -> bf16 [L][C] transpose+convert ----------------
__global__ __launch_bounds__(256) void transpose_cvt(const float* __restrict__ X,
                                                     u16* __restrict__ Xt) {
  __shared__ float tl[64][65];
  const int n = blockIdx.z, l0 = blockIdx.x * 64, c0 = blockIdx.y * 64;
  const int t = threadIdx.x;
  const int rr = t >> 4;           // 0..15
  const int lc = (t & 15) * 4;
  const float* Xn = X + (size_t)n * C * LL;
#pragma unroll
  for (int p = 0; p < 4; ++p) {
    const int row = p * 16 + rr;  // c within tile
    float4 v = *(const float4*)&Xn[(size_t)(c0 + row) * LL + l0 + lc];
    tl[row][lc + 0] = v.x; tl[row][lc + 1] = v.y;
    tl[row][lc + 2] = v.z; tl[row][lc + 3] = v.w;
  }
  __syncthreads();
  u16* XtN = Xt + (size_t)n * LL * C;
  const int cc = (t & 15) * 4;
#pragma unroll
  for (int p = 0; p < 4; ++p) {
    const int lrow = p * 16 + rr;  // l within tile
    ushort4 o;
    o.x = f2bf(tl[cc + 0][lrow]); o.y = f2bf(tl[cc + 1][lrow]);
    o.z = f2bf(tl[cc + 2][lrow]); o.w = f2bf(tl[cc + 3][lrow]);
    *(ushort4*)&XtN[(size_t)(l0 + lrow) * C + c0 + cc] = o;
  }
}

// ---------------- fp32 -> bf16 flat convert (for 256x256 weights) ----------------
__global__ __launch_bounds__(256) void cvt_bf16(const float* __restrict__ src,
                                                u16* __restrict__ dst) {
  const int i = (blockIdx.x * 256 + threadIdx.x) * 4;
  float4 v = *(const float4*)&src[i];
  ushort4 o = {f2bf(v.x), f2bf(v.y), f2bf(v.z), f2bf(v.w)};
  *(ushort4*)&dst[i] = o;
}

// ---------------- proj: Pt[l][co] = sum_k Xt[l][k]*W[co][k] + b, bf16 out ----------------
// 128x128 tile, BK=32, 4 waves 2x2, each wave 64x64 = 4x4 MFMA 16x16x32 tiles.
__global__ __launch_bounds__(256) void proj_mfma(const u16* __restrict__ Xt,
    const u16* __restrict__ Wb, const float* __restrict__ bias,
    u16* __restrict__ Pt) {
  __shared__ __align__(16) u16 As[4096];  // [128 l][32 k]
  __shared__ __align__(16) u16 Bs[4096];  // [128 co][32 k]
  const int n = blockIdx.z;
  const int l0 = blockIdx.x * 128;
  const int co0 = blockIdx.y * 128;
  const int t = threadIdx.x;
  const int lane = t & 63, wave = t >> 6;
  const int wm = (wave >> 1) * 64, wn = (wave & 1) * 64;
  const int srow = t >> 2;         // staging row 0..63
  const int scol = (t & 3) * 8;    // staging k offset
  const u16* XtN = Xt + (size_t)n * LL * C;
  f32x4 acc[4][4] = {};
  for (int k0 = 0; k0 < C; k0 += 32) {
    __syncthreads();
    gload_lds16(&XtN[(size_t)(l0 + srow) * C + k0 + scol], &As[wave * 512]);
    gload_lds16(&XtN[(size_t)(l0 + 64 + srow) * C + k0 + scol], &As[2048 + wave * 512]);
    gload_lds16(&Wb[(size_t)(co0 + srow) * C + k0 + scol], &Bs[wave * 512]);
    gload_lds16(&Wb[(size_t)(co0 + 64 + srow) * C + k0 + scol], &Bs[2048 + wave * 512]);
    __syncthreads();
    const int fr = lane & 15, quad = lane >> 4;
    bf16x8 a[4], b[4];
#pragma unroll
    for (int i = 0; i < 4; ++i)
      a[i] = *(const bf16x8*)&As[(wm + i * 16 + fr) * 32 + quad * 8];
#pragma unroll
    for (int j = 0; j < 4; ++j)
      b[j] = *(const bf16x8*)&Bs[(wn + j * 16 + fr) * 32 + quad * 8];
#pragma unroll
    for (int i = 0; i < 4; ++i)
#pragma unroll
      for (int j = 0; j < 4; ++j)
        acc[i][j] = __builtin_amdgcn_mfma_f32_16x16x32_bf16(a[i], b[j], acc[i][j], 0, 0, 0);
  }
  u16* PtN = Pt + (size_t)n * LL * C;
  const int fr = lane & 15, quad = lane >> 4;
  const int colc = co0 + wn + fr;
  float bv[4];
#pragma unroll
  for (int j = 0; j < 4; ++j) bv[j] = bias[colc + j * 16];
#pragma unroll
  for (int i = 0; i < 4; ++i) {
    const int lrow = l0 + wm + i * 16 + quad * 4;
#pragma unroll
    for (int r = 0; r < 4; ++r)
#pragma unroll
      for (int j = 0; j < 4; ++j)
        PtN[(size_t)(lrow + r) * C + colc + j * 16] = f2bf(acc[i][j][r] + bv[j]);
  }
}

// ---------------- k stats over [L][C]: per-chunk max + sumexp partials ----------------
__global__ __launch_bounds__(256) void kstats(const u16* __restrict__ Kt,
    float* __restrict__ pmax, float* __restrict__ psum) {
  const int chk = blockIdx.x, n = blockIdx.y;
  const int t = threadIdx.x;
  const int c2 = t & 127, ph = t >> 7;
  const u16* base = Kt + ((size_t)n * LL + chk * 256) * C + c2 * 2;
  float m0 = -1e30f, m1 = -1e30f;
  for (int i = 0; i < 128; ++i) {
    u32 u = *(const u32*)&base[(size_t)(2 * i + ph) * C];
    m0 = fmaxf(m0, bf2f(u & 0xffffu)); m1 = fmaxf(m1, bf2f(u >> 16));
  }
  __shared__ float sm[2][256];
  sm[ph][c2 * 2] = m0; sm[ph][c2 * 2 + 1] = m1;
  __syncthreads();
  m0 = fmaxf(sm[0][c2 * 2], sm[1][c2 * 2]);
  m1 = fmaxf(sm[0][c2 * 2 + 1], sm[1][c2 * 2 + 1]);
  float s0 = 0.f, s1 = 0.f;
  for (int i = 0; i < 128; ++i) {
    u32 u = *(const u32*)&base[(size_t)(2 * i + ph) * C];
    s0 += __expf(bf2f(u & 0xffffu) - m0);
    s1 += __expf(bf2f(u >> 16) - m1);
  }
  __syncthreads();
  sm[ph][c2 * 2] = s0; sm[ph][c2 * 2 + 1] = s1;
  __syncthreads();
  if (ph == 0) {
    const int idx = (n * KCHUNKS + chk) * 256 + c2 * 2;
    pmax[idx] = m0; pmax[idx + 1] = m1;
    psum[idx] = sm[0][c2 * 2] + sm[1][c2 * 2];
    psum[idx + 1] = sm[0][c2 * 2 + 1] + sm[1][c2 * 2 + 1];
  }
}

__global__ __launch_bounds__(256) void kmerge(const float* __restrict__ pmax,
    const float* __restrict__ psum, float* __restrict__ kmax, float* __restrict__ krs) {
  const int n = blockIdx.x, c = threadIdx.x;
  float m = -1e30f;
  for (int ch = 0; ch < KCHUNKS; ++ch)
    m = fmaxf(m, pmax[(n * KCHUNKS + ch) * 256 + c]);
  float s = 0.f;
  for (int ch = 0; ch < KCHUNKS; ++ch)
    s += psum[(n * KCHUNKS + ch) * 256 + c] * __expf(pmax[(n * KCHUNKS + ch) * 256 + c] - m);
  kmax[n * 256 + c] = m;
  krs[n * 256 + c] = 1.0f / s;
}

// ---------------- q softmax over 32 head-channels, [L][C] layout, in place ----------------
__global__ __launch_bounds__(256) void qsoftmax(u16* __restrict__ Qt) {
  const int t = threadIdx.x;
  const int lane = t & 63, wave = t >> 6;
  const int g = lane >> 2, sub = lane & 3;
  const int gid = (blockIdx.x * 4 + wave) * 16 + g;  // 0..NB*LL*HEADS-1
  const int h = gid & 7;
  const size_t row = (size_t)(gid >> 3);
  u16* p = Qt + row * C + h * 32 + sub * 8;
  uint4 u = *(const uint4*)p;
  float v[8]; unpack8(u, v);
  float m = v[0];
#pragma unroll
  for (int j = 1; j < 8; ++j) m = fmaxf(m, v[j]);
  m = fmaxf(m, __shfl_xor(m, 1));
  m = fmaxf(m, __shfl_xor(m, 2));
  float e[8], s = 0.f;
#pragma unroll
  for (int j = 0; j < 8; ++j) { e[j] = __expf(v[j] - m); s += e[j]; }
  s += __shfl_xor(s, 1);
  s += __shfl_xor(s, 2);
  const float r = 1.0f / s;
  union { uint4 u; u16 h[8]; } o;
#pragma unroll
  for (int j = 0; j < 8; ++j) o.h[j] = f2bf(e[j] * r);
  *(uint4*)p = o.u;
}

// ---------------- context partials from [L][C]: ctx[k,v] += Ksm[l,k]*V[l,v] ----------------
__global__ __launch_bounds__(64) void ctx_partial(const u16* __restrict__ Kt,
    const u16* __restrict__ Vt, const float* __restrict__ kmax,
    const float* __restrict__ krs, float* __restrict__ part) {
  __shared__ float Ks[32][36];
  __shared__ float Vs[32][36];
  const int nh = blockIdx.y, chk = blockIdx.x;
  const int n = nh >> 3, h = nh & 7;
  const int lane = threadIdx.x;
  const int rr = lane >> 2, koff = (lane & 3) * 8;
  float km[8];
#pragma unroll
  for (int j = 0; j < 8; ++j) km[j] = kmax[n * C + h * 32 + koff + j];
  const size_t rowbase = ((size_t)n * LL + chk * CHUNK) * C + h * 32 + koff;
  const int k4 = (lane & 7) * 4, v4 = (lane >> 3) * 4;
  float acc[4][4];
#pragma unroll
  for (int i = 0; i < 4; ++i)
#pragma unroll
    for (int j = 0; j < 4; ++j) acc[i][j] = 0.f;
  for (int ls = 0; ls < CHUNK; ls += 32) {
    __syncthreads();
#pragma unroll
    for (int p = 0; p < 2; ++p) {
      const int r = p * 16 + rr;
      uint4 ku = *(const uint4*)&Kt[rowbase + (size_t)(ls + r) * C];
      uint4 vu = *(const uint4*)&Vt[rowbase + (size_t)(ls + r) * C];
      float kf[8], vf[8];
      unpack8(ku, kf); unpack8(vu, vf);
#pragma unroll
      for (int j = 0; j < 8; ++j) {
        Ks[r][koff + j] = __expf(kf[j] - km[j]);
        Vs[r][koff + j] = vf[j];
      }
    }
    __syncthreads();
#pragma unroll
    for (int l = 0; l < 32; ++l) {
      float a[4], b[4];
      *(float4*)a = *(const float4*)&Ks[l][k4];
      *(float4*)b = *(const float4*)&Vs[l][v4];
#pragma unroll
      for (int i = 0; i < 4; ++i)
#pragma unroll
        for (int j = 0; j < 4; ++j) acc[i][j] = fmaf(a[i], b[j], acc[i][j]);
    }
  }
#pragma unroll
  for (int i = 0; i < 4; ++i) {
    const float rs = krs[n * C + h * 32 + k4 + i];
#pragma unroll
    for (int j = 0; j < 4; ++j)
      part[(((size_t)chk * NH + nh) * HC + k4 + i) * HC + v4 + j] = acc[i][j] * rs;
  }
}

__global__ __launch_bounds__(256) void ctx_reduce(const float* __restrict__ part,
                                                  float* __restrict__ ctx) {
  const int idx = blockIdx.x * 256 + threadIdx.x;  // < NH*HC*HC
  float s = 0.f;
  for (int c = 0; c < CH; ++c) s += part[(size_t)c * (NH * HC * HC) + idx];
  ctx[idx] = s;
}

// ---------------- fuse: M_n[o, h*32+k] = sum_v Wr[o, h*32+v]*ctx[n,h,k,v], bf16 out ----------------
__global__ __launch_bounds__(256) void mfuse(const float* __restrict__ Wr,
    const float* __restrict__ ctx, u16* __restrict__ M) {
  const int idx = blockIdx.x * 256 + threadIdx.x;  // < NB*C*C
  const int hk = idx & 255;
  const int o = (idx >> 8) & 255;
  const int n = idx >> 16;
  const int h = hk >> 5, k = hk & 31;
  const float* wr = Wr + (size_t)o * C + h * HC;
  const float* cx = ctx + ((size_t)(n * HEADS + h) * HC + k) * HC;
  float s = 0.f;
#pragma unroll
  for (int v = 0; v < HC; ++v) s = fmaf(wr[v], cx[v], s);
  M[idx] = f2bf(s);
}

// ---------------- out[co][l] = sum_k M[co][k]*Qt[l][k] + br[co] + Xq[co][l], fp32 ----------------
__global__ __launch_bounds__(256) void out_mfma(const u16* __restrict__ Qt,
    const u16* __restrict__ Mb, const float* __restrict__ br,
    const float* __restrict__ Xq, float* __restrict__ out) {
  __shared__ __align__(16) u16 As[4096];  // [128 co][32 k]
  __shared__ __align__(16) u16 Bs[4096];  // [128 l][32 k]
  const int n = blockIdx.z;
  const int l0 = blockIdx.x * 128;
  const int co0 = blockIdx.y * 128;
  const int t = threadIdx.x;
  const int lane = t & 63, wave = t >> 6;
  const int wm = (wave >> 1) * 64, wn = (wave & 1) * 64;
  const int srow = t >> 2;
  const int scol = (t & 3) * 8;
  const u16* MbN = Mb + (size_t)n * C * C;
  const u16* QtN = Qt + (size_t)n * LL * C;
  f32x4 acc[4][4] = {};
  for (int k0 = 0; k0 < C; k0 += 32) {
    __syncthreads();
    gload_lds16(&MbN[(size_t)(co0 + srow) * C + k0 + scol], &As[wave * 512]);
    gload_lds16(&MbN[(size_t)(co0 + 64 + srow) * C + k0 + scol], &As[2048 + wave * 512]);
    gload_lds16(&QtN[(size_t)(l0 + srow) * C + k0 + scol], &Bs[wave * 512]);
    gload_lds16(&QtN[(size_t)(l0 + 64 + srow) * C + k0 + scol], &Bs[2048 + wave * 512]);
    __syncthreads();
    const int fr = lane & 15, quad = lane >> 4;
    bf16x8 a[4], b[4];
#pragma unroll
    for (int i = 0; i < 4; ++i)
      a[i] = *(const bf16x8*)&As[(wm + i * 16 + fr) * 32 + quad * 8];
#pragma unroll
    for (int j = 0; j < 4; ++j)
      b[j] = *(const bf16x8*)&Bs[(wn + j * 16 + fr) * 32 + quad * 8];
#pragma unroll
    for (int i = 0; i < 4; ++i)
#pragma unroll
      for (int j = 0; j < 4; ++j)
        acc[i][j] = __builtin_amdgcn_mfma_f32_16x16x32_bf16(a[i], b[j], acc[i][j], 0, 0, 0);
  }
  const float* XqN = Xq + (size_t)n * C * LL;
  float* On = out + (size_t)n * C * LL;
  const int fr = lane & 15, quad = lane >> 4;
#pragma unroll
  for (int i = 0; i < 4; ++i) {
#pragma unroll
    for (int r = 0; r < 4; ++r) {
      const int co = co0 + wm + i * 16 + quad * 4 + r;
      const float bb = br[co];
#pragma unroll
      for (int j = 0; j < 4; ++j) {
        const int l = l0 + wn + j * 16 + fr;
        const size_t off = (size_t)co * LL + l;
        On[off] = acc[i][j][r] + bb + XqN[off];
      }
    }
  }
}

extern "C" void kernel_launch(void* const* d_in, const int* in_sizes, int n_in,
                              void* d_out, int out_size, void* d_ws, size_t ws_size,
                              hipStream_t stream) {
  const float* Xq = (const float*)d_in[0];
  const float* Xk = (const float*)d_in[1];
  const float* Xv = (const float*)d_in[2];
  const float* Wq = (const float*)d_in[3];
  const float* bq = (const float*)d_in[4];
  const float* Wk = (const float*)d_in[5];
  const float* bk = (const float*)d_in[6];
  const float* Wv = (const float*)d_in[7];
  const float* bv = (const float*)d_in[8];
  const float* Wr = (const float*)d_in[9];
  const float* br = (const float*)d_in[10];
  float* out = (float*)d_out;

  char* ws = (char*)d_ws;
  const size_t nelem = (size_t)NB * LL * C;  // per [L][C] buffer
  u16* Xt = (u16*)ws;                        // reused for all 3 inputs
  u16* Qt = (u16*)(ws + nelem * 2);
  u16* Kt = (u16*)(ws + nelem * 4);
  u16* Vt = (u16*)(ws + nelem * 6);
  char* p = ws + nelem * 8;
  u16* Wqb = (u16*)p; p += C * C * 2;
  u16* Wkb = (u16*)p; p += C * C * 2;
  u16* Wvb = (u16*)p; p += C * C * 2;
  u16* Mb = (u16*)p;  p += (size_t)NB * C * C * 2;
  float* pmax = (float*)p; p += KCHUNKS * NB * C * 4;
  float* psum = (float*)p; p += KCHUNKS * NB * C * 4;
  float* kmax = (float*)p; p += NB * C * 4;
  float* krs = (float*)p;  p += NB * C * 4;
  float* ctx = (float*)p;  p += NH * HC * HC * 4;
  float* part = (float*)p;

  const dim3 gT(100, 4, NB);   // transpose
  const dim3 gG(50, 2, NB);    // 128x128 GEMM tiles

  cvt_bf16<<<64, 256, 0, stream>>>(Wq, Wqb);
  cvt_bf16<<<64, 256, 0, stream>>>(Wk, Wkb);
  cvt_bf16<<<64, 256, 0, stream>>>(Wv, Wvb);

  transpose_cvt<<<gT, 256, 0, stream>>>(Xq, Xt);
  proj_mfma<<<gG, 256, 0, stream>>>(Xt, Wqb, bq, Qt);
  transpose_cvt<<<gT, 256, 0, stream>>>(Xk, Xt);
  proj_mfma<<<gG, 256, 0, stream>>>(Xt, Wkb, bk, Kt);
  transpose_cvt<<<gT, 256, 0, stream>>>(Xv, Xt);
  proj_mfma<<<gG, 256, 0, stream>>>(Xt, Wvb, bv, Vt);

  qsoftmax<<<NB * LL * HEADS / 64, 256, 0, stream>>>(Qt);
  kstats<<<dim3(KCHUNKS, NB), 256, 0, stream>>>(Kt, pmax, psum);
  kmerge<<<NB, 256, 0, stream>>>(pmax, psum, kmax, krs);
  ctx_partial<<<dim3(CH, NH), 64, 0, stream>>>(Kt, Vt, kmax, krs, part);
  ctx_reduce<<<NH * HC * HC / 256, 256, 0, stream>>>(part, ctx);
  mfuse<<<NB * C * C / 256, 256, 0, stream>>>(Wr, ctx, Mb);
  out_mfma<<<gG, 256, 0, stream>>>(Qt, Mb, br, Xq, out);
}